// Round 15
// baseline (78.086 us; speedup 1.0000x reference)
//
#include <hip/hip_runtime.h>
#include <cstdint>
#include <cstddef>

typedef float v16f __attribute__((ext_vector_type(16)));
typedef short v8s  __attribute__((ext_vector_type(8)));

#define MFMA32(A,B,C) __builtin_amdgcn_mfma_f32_32x32x16_bf16((A),(B),(C),0,0,0)
#define THRU 1e-3f

__device__ __forceinline__ unsigned f2bf(float f) {
  unsigned u = __builtin_bit_cast(unsigned, f);
  u += 0x7FFFu + ((u >> 16) & 1u);
  return u >> 16;
}
__device__ __forceinline__ float bf2f(unsigned us) {
  return __builtin_bit_cast(float, us << 16);
}
__device__ __forceinline__ void gload16(const void* g, void* l) {
  __builtin_amdgcn_global_load_lds(
      (const __attribute__((address_space(1))) void*)g,
      (__attribute__((address_space(3))) void*)l, 16, 0, 0);
}

// ---------------------------------------------------------------------------
// prep: h = x @ W^T + b; bf16 h/m splits of x in MFMA-tiled layout
// frag[b][t=node/32][kc][lane]{16B}; EFl per-i {El,Fl}; EFrp head-pair
// {Er,Fr,Er',Fr'}; h stored as PV-B-FRAGMENT tiles vt[b][h][jt][f][lane]{8bf16}
// (r11-verified layout: lane&31 = c-col, k = f*16 + (lane>>5)*8 + e).
// ---------------------------------------------------------------------------
__global__ __launch_bounds__(256) void gat_prep(
    const float* __restrict__ nf, const float* __restrict__ Wm,
    const float* __restrict__ bias, const float* __restrict__ aw,
    unsigned short* __restrict__ nfh, unsigned short* __restrict__ nfm,
    unsigned short* __restrict__ vt,
    float* __restrict__ EFl, float* __restrict__ EFrp)
{
  __shared__ float xl[32][132];
  const int tid = threadIdx.x;
  const int row = tid & 31, g = tid >> 5;
  const int r0 = blockIdx.x * 32;          // global node row base (0..8191)
  const int b = r0 >> 11, n0 = r0 & 2047;
  const int d0 = g * 16;

  float x[16];
  {
    const float* xp = nf + (size_t)(r0 + row) * 128 + d0;
#pragma unroll
    for (int q = 0; q < 4; ++q) {
      float4 v = *(const float4*)(xp + 4 * q);
      x[4*q+0] = v.x; x[4*q+1] = v.y; x[4*q+2] = v.z; x[4*q+3] = v.w;
    }
  }
  {
    unsigned hu[16], mu[16];
#pragma unroll
    for (int q = 0; q < 16; ++q) {
      xl[row][d0 + q] = x[q];
      unsigned hb = f2bf(x[q]); float hf = bf2f(hb);
      unsigned mb = f2bf(x[q] - hf);
      hu[q] = hb; mu[q] = mb;
    }
    // tiled fragment store: (b, t=n0>>5, kc=g, lane=row)
    const size_t to = ((size_t)(b * 64 + (n0 >> 5)) * 8 + g) * 512 + row * 8;
    uint4 p0, p1;
    p0.x = hu[0] | (hu[1] << 16);  p0.y = hu[2] | (hu[3] << 16);
    p0.z = hu[4] | (hu[5] << 16);  p0.w = hu[6] | (hu[7] << 16);
    p1.x = hu[8] | (hu[9] << 16);  p1.y = hu[10] | (hu[11] << 16);
    p1.z = hu[12] | (hu[13] << 16); p1.w = hu[14] | (hu[15] << 16);
    *(uint4*)(nfh + to) = p0; *(uint4*)(nfh + to + 256) = p1;
    p0.x = mu[0] | (mu[1] << 16);  p0.y = mu[2] | (mu[3] << 16);
    p0.z = mu[4] | (mu[5] << 16);  p0.w = mu[6] | (mu[7] << 16);
    p1.x = mu[8] | (mu[9] << 16);  p1.y = mu[10] | (mu[11] << 16);
    p1.z = mu[12] | (mu[13] << 16); p1.w = mu[14] | (mu[15] << 16);
    *(uint4*)(nfm + to) = p0; *(uint4*)(nfm + to + 256) = p1;
  }
  __syncthreads();

  float acc[16];
  const int ob = g * 16;
#pragma unroll
  for (int o = 0; o < 16; ++o) acc[o] = bias[ob + o];
  for (int dd = 0; dd < 128; dd += 4) {
    float4 xq = *(const float4*)&xl[row][dd];
#pragma unroll
    for (int o = 0; o < 16; ++o) {
      float4 wq = *(const float4*)(Wm + (size_t)(ob + o) * 128 + dd);
      acc[o] = fmaf(xq.x, wq.x, acc[o]);
      acc[o] = fmaf(xq.y, wq.y, acc[o]);
      acc[o] = fmaf(xq.z, wq.z, acc[o]);
      acc[o] = fmaf(xq.w, wq.w, acc[o]);
    }
  }
  // PV-B-fragment store (r11-verified): j=n0+row; f=(row>>4)&1, kh=(row>>3)&1
  {
    const int f = (row >> 4) & 1, kh = (row >> 3) & 1, e = row & 7;
#pragma unroll
    for (int o = 0; o < 16; ++o) {
      const int c = ob + o, hh2 = c >> 5, cc = c & 31;
      const size_t va = (((size_t)(b * 4 + hh2) * 64 + (n0 >> 5)) * 2 + f) * 512
                        + (kh * 32 + cc) * 8 + e;
      vt[va] = (unsigned short)f2bf(acc[o]);
    }
  }

  const int hh = g >> 1, cb = (g & 1) * 16;
  float sl = 0.f, sr = 0.f;
#pragma unroll
  for (int o = 0; o < 16; ++o) {
    sl = fmaf(acc[o], aw[hh * 64 + cb + o], sl);
    sr = fmaf(acc[o], aw[hh * 64 + 32 + cb + o], sr);
  }
  sl += __shfl_xor(sl, 32, 64);
  sr += __shfl_xor(sr, 32, 64);
  if (!(g & 1)) {
    const float L2E = 1.4426950408889634f;
    float El = exp2f(sl * L2E), Fl = exp2f(sl * (0.3f * L2E));
    float Er = exp2f(sr * L2E), Fr = exp2f(sr * (0.3f * L2E));
    size_t nn = (size_t)(r0 + row);
    EFl[nn * 8 + hh]     = El;
    EFl[nn * 8 + 4 + hh] = Fl;
    // head-pair layout: {Er(2p), Fr(2p), Er(2p+1), Fr(2p+1)} per 16B
    EFrp[nn * 8 + (hh >> 1) * 4 + (hh & 1) * 2]     = Er;
    EFrp[nn * 8 + (hh >> 1) * 4 + (hh & 1) * 2 + 1] = Fr;
  }
}

// ---------------------------------------------------------------------------
// mask: 3-pass split-bf16. A-side (j) fragments staged to LDS via
// global_load_lds (zero VGPR cost -> full MLP: all 32KB in flight at once,
// one barrier), then conflict-free ds_read_b128 operands. B-side (i) held in
// registers (latency hidden under the staging barrier). Sign bits + min|S|;
// |S|<THR lanes recompute exact f64 dot inline and patch their bit.
// mask layout: u32 mask[b][j>>5][i], bit = j&31.
// LDS region c = s*8+kc (s: 0=h/t0,1=h/t1,2=m/t0,3=m/t1): 32 x 1KB = 32KB.
// ---------------------------------------------------------------------------
__global__ __launch_bounds__(256) void gat_mask(
    const unsigned short* __restrict__ nfh, const unsigned short* __restrict__ nfm,
    const float* __restrict__ nf, unsigned* __restrict__ mask)
{
  __shared__ __align__(16) char smA[32768];
  const int tid = threadIdx.x, lane = tid & 63, wv = tid >> 6;
  const int li = lane & 31, hi = lane >> 5;
  const int blk = blockIdx.x;
  const int jb = blk & 31, t = blk >> 5;
  const int ib = t & 15, b = t >> 4;
  const int i0 = ib * 128 + wv * 32;
  const int j0 = jb * 64;

  const size_t lbyte = (size_t)lane * 8;   // ushort offset of lane's 16B frag
  const size_t tiB = ((size_t)(b * 64 + (i0 >> 5)) * 8) * 512 + lbyte;
  const size_t tj0 = ((size_t)(b * 64 + (j0 >> 5)) * 8) * 512;   // no lane term

  // stage A fragments: 32 combos (s,kc) x 64 lanes, 8 gload16 per thread
#pragma unroll
  for (int q = 0; q < 8; ++q) {
    const int c = q * 4 + wv;              // 0..31
    const int s = c >> 3, kc = c & 7;
    const unsigned short* src = (s < 2) ? nfh : nfm;
    const size_t go = tj0 + (size_t)(s & 1) * 4096 + kc * 512 + lbyte;
    gload16((const char*)(src + go), smA + c * 1024 + lane * 16);
  }

  // per-wave B fragments (direct global; latency overlaps staging + barrier)
  v8s BH[8], BM[8];
#pragma unroll
  for (int kc = 0; kc < 8; ++kc) {
    BH[kc] = *(const v8s*)(nfh + tiB + kc * 512);
    BM[kc] = *(const v8s*)(nfm + tiB + kc * 512);
  }
  __syncthreads();   // drains gload_lds + BH/BM vmem

  v16f S0, S1;
#pragma unroll
  for (int r = 0; r < 16; ++r) { S0[r] = 0.f; S1[r] = 0.f; }
  {
    const char* base = smA + lane * 16;
#pragma unroll
    for (int kc = 0; kc < 8; ++kc) {
      v8s A0h = *(const v8s*)(base + kc * 1024);
      v8s A1h = *(const v8s*)(base + (8 + kc) * 1024);
      v8s A0m = *(const v8s*)(base + (16 + kc) * 1024);
      v8s A1m = *(const v8s*)(base + (24 + kc) * 1024);
      S0 = MFMA32(A0h, BH[kc], S0);
      S1 = MFMA32(A1h, BH[kc], S1);
      S0 = MFMA32(A0h, BM[kc], S0);
      S1 = MFMA32(A1h, BM[kc], S1);
      S0 = MFMA32(A0m, BH[kc], S0);
      S1 = MFMA32(A1m, BH[kc], S1);
    }
  }

  unsigned u0 = 0, u1 = 0;
  float mn = 1e30f;
  const int sh = hi * 4;
#pragma unroll
  for (int r = 0; r < 16; ++r) {
    const int jlc = (r & 3) + 8 * (r >> 2);
    const unsigned bit = (1u << jlc) << sh;
    if (S0[r] > 0.f) u0 |= bit;
    if (S1[r] > 0.f) u1 |= bit;
    mn = fminf(mn, fabsf(S0[r]));
    mn = fminf(mn, fabsf(S1[r]));
  }

  if (mn < THRU) {
    const float* xi = nf + ((size_t)b * 2048 + i0 + li) * 128;
#pragma unroll
    for (int sub = 0; sub < 2; ++sub) {
#pragma unroll
      for (int r = 0; r < 16; ++r) {
        const float s = sub ? S1[r] : S0[r];
        if (fabsf(s) < THRU) {
          const int jlc = (r & 3) + 8 * (r >> 2);
          const int j = j0 + sub * 32 + jlc + 4 * hi;
          const float* xj = nf + ((size_t)b * 2048 + j) * 128;
          double a = 0.0;
          for (int k = 0; k < 128; k += 2) {
            a = fma((double)xi[k],     (double)xj[k],     a);
            a = fma((double)xi[k + 1], (double)xj[k + 1], a);
          }
          const unsigned bit = (1u << jlc) << sh;
          if (sub == 0) u0 = (a > 0.0) ? (u0 | bit) : (u0 & ~bit);
          else          u1 = (a > 0.0) ? (u1 | bit) : (u1 & ~bit);
        }
      }
    }
  }

  unsigned f0 = u0 | (unsigned)__shfl_xor((int)u0, 32, 64);
  unsigned f1 = u1 | (unsigned)__shfl_xor((int)u1, 32, 64);
  if (hi == 0) {
    mask[(size_t)(b * 64 + jb * 2)     * 2048 + i0 + li] = f0;
    mask[(size_t)(b * 64 + jb * 2 + 1) * 2048 + i0 + li] = f1;
  }
}

// ---------------------------------------------------------------------------
// attn (r13 hybrid — kept): head-pair split, CH chunks; V = direct-global
// B-fragment loads from vt (L2-resident chunk shared by XCD-grouped blocks);
// EF staged to LDS ONCE (4KB, one barrier total); mask words in registers.
// Main loop: zero barriers, zero LDS-V reads.
// ---------------------------------------------------------------------------
#define PVREG(pw, h, Va, Vb)                                                   \
  {                                                                            \
    auto q0 = __builtin_amdgcn_permlane32_swap((int)pw[0], (int)pw[2], false, false); \
    auto q1 = __builtin_amdgcn_permlane32_swap((int)pw[1], (int)pw[3], false, false); \
    auto q2 = __builtin_amdgcn_permlane32_swap((int)pw[4], (int)pw[6], false, false); \
    auto q3 = __builtin_amdgcn_permlane32_swap((int)pw[5], (int)pw[7], false, false); \
    uint4 c0, c1;                                                              \
    c0.x = (unsigned)q0[0]; c0.y = (unsigned)q1[0];                            \
    c0.z = (unsigned)q0[1]; c0.w = (unsigned)q1[1];                            \
    c1.x = (unsigned)q2[0]; c1.y = (unsigned)q3[0];                            \
    c1.z = (unsigned)q2[1]; c1.w = (unsigned)q3[1];                            \
    v8s P0 = __builtin_bit_cast(v8s, c0);                                      \
    v8s P1 = __builtin_bit_cast(v8s, c1);                                      \
    acc[h] = MFMA32(P0, (Va), acc[h]);                                         \
    acc[h] = MFMA32(P1, (Vb), acc[h]);                                         \
  }

template<int CH>
__global__ __launch_bounds__(256, 2) void gat_attn(
    const unsigned short* __restrict__ vt, const float* __restrict__ EFl,
    const float* __restrict__ EFrp, const unsigned* __restrict__ mask,
    float* __restrict__ nump, float* __restrict__ denp)
{
  constexpr int JPC = 2048 / CH;       // j per chunk
  constexpr int NT = JPC >> 5;         // 32-j tiles per chunk
  __shared__ __align__(16) char sm[JPC * 16];   // EF: 16B per j-node

  const int tid = threadIdx.x, lane = tid & 63, wv = tid >> 6;
  const int li = lane & 31, hi = lane >> 5;

  // XCD swizzle: blocks sharing (b,ch,hp2) — same V/EF chunk — on one XCD.
  const int blk = blockIdx.x;
  const int x = blk & 7, y = blk >> 3;
  const int ig = y & 15;
  const int combo = x * CH + (y >> 4);       // 0..8*CH-1
  const int hp2 = combo & 1;                 // head pair (heads 2hp2, 2hp2+1)
  const int r2 = combo >> 1;
  const int ch = r2 % CH, b = r2 / CH;

  const size_t nb = (size_t)b * 2048;
  const int i0 = ig * 128 + wv * 32;
  const int j0 = ch * JPC;

  float EL[2], FL[2];
  {
    const float* p = EFl + (nb + i0 + li) * 8 + 2 * hp2;
    float2 e = *(const float2*)p;
    float2 f = *(const float2*)(p + 4);
    EL[0] = e.x; EL[1] = e.y; FL[0] = f.x; FL[1] = f.y;
  }

  // prefetch ALL mask words for this wave's i-rows x full j-range
  unsigned mw[NT];
#pragma unroll
  for (int q = 0; q < NT; ++q)
    mw[q] = mask[(size_t)(b * 64 + (j0 >> 5) + q) * 2048 + i0 + li] >> (hi * 4);

  // EF: whole chunk staged once (JPC nodes x 16B)
  for (int q = tid; q < JPC; q += 256)
    gload16((const char*)EFrp + (size_t)(nb + j0 + q) * 32 + (hp2 << 4),
            sm + q * 16);

  v16f acc[2];
#pragma unroll
  for (int h = 0; h < 2; ++h)
#pragma unroll
    for (int r = 0; r < 16; ++r) acc[h][r] = 0.f;
  float den[2] = {0.f, 0.f};

  // V fragment bases (head 2*hp2 and 2*hp2+1); 1KB per (tile,f-half)
  const unsigned short* vb0 =
      vt + ((size_t)(b * 4 + 2 * hp2) * 64 + (j0 >> 5)) * 1024 + (size_t)lane * 8;
  const unsigned short* vb1 = vb0 + 65536;

  __syncthreads();   // EF staged (drains gload_lds)

#pragma unroll 2
  for (int it2 = 0; it2 < NT; ++it2) {
    const unsigned mh = mw[it2];
    v8s V00 = *(const v8s*)(vb0 + it2 * 1024);
    v8s V01 = *(const v8s*)(vb0 + it2 * 1024 + 512);
    v8s V10 = *(const v8s*)(vb1 + it2 * 1024);
    v8s V11 = *(const v8s*)(vb1 + it2 * 1024 + 512);
    const char* Eb = sm + (it2 << 9);
    unsigned pA[8], pB[8];
#pragma unroll
    for (int rp = 0; rp < 8; ++rp) {
      const int r0 = 2 * rp;
      const int jl0c = (r0 & 3) + 8 * (r0 >> 2);
      const int nA = (jl0c + 4 * hi) * 16;
      float4 e0 = *(const float4*)(Eb + nA);        // {Er0,Fr0,Er1,Fr1}
      float4 e1 = *(const float4*)(Eb + nA + 16);   // node jl0c+1
      const bool m0 = (mh >> jl0c) & 1;
      const bool m1 = (mh >> (jl0c + 1)) & 1;
      float wA0 = fmaxf(e0.x * EL[0], e0.y * FL[0]); wA0 = m0 ? wA0 : 0.f;
      float wB0 = fmaxf(e0.z * EL[1], e0.w * FL[1]); wB0 = m0 ? wB0 : 0.f;
      float wA1 = fmaxf(e1.x * EL[0], e1.y * FL[0]); wA1 = m1 ? wA1 : 0.f;
      float wB1 = fmaxf(e1.z * EL[1], e1.w * FL[1]); wB1 = m1 ? wB1 : 0.f;
      den[0] += wA0 + wA1;
      den[1] += wB0 + wB1;
      asm("v_cvt_pk_bf16_f32 %0, %1, %2" : "=v"(pA[rp]) : "v"(wA0), "v"(wA1));
      asm("v_cvt_pk_bf16_f32 %0, %1, %2" : "=v"(pB[rp]) : "v"(wB0), "v"(wB1));
    }
    PVREG(pA, 0, V00, V01)
    PVREG(pB, 1, V10, V11)
  }

#pragma unroll
  for (int h = 0; h < 2; ++h) den[h] += __shfl_xor(den[h], 32, 64);

  const size_t obase = ((size_t)b * CH + ch) * 2048 + i0;
#pragma unroll
  for (int h = 0; h < 2; ++h) {
#pragma unroll
    for (int r = 0; r < 16; ++r) {
      const int il = (r & 3) + 8 * (r >> 2) + 4 * hi;
      nump[(obase + il) * 128 + (hp2 * 2 + h) * 32 + li] = acc[h][r];
    }
  }
  if (lane < 32) {
    float2 dv; dv.x = den[0]; dv.y = den[1];
    *(float2*)(denp + (obase + li) * 4 + 2 * hp2) = dv;
  }
}

// ---------------------------------------------------------------------------
// reduce: out = (sum_ch num) / (sum_ch den), float4-vectorized.
// ---------------------------------------------------------------------------
__global__ __launch_bounds__(256) void gat_reduce(
    const float* __restrict__ nump, const float* __restrict__ denp,
    float* __restrict__ out, const int CH)
{
  const int t = blockIdx.x * 256 + threadIdx.x;   // < 262144
  const int b = t >> 16;
  const int rem = t & 65535;
  const int n = rem >> 5;
  const int col = (rem & 31) * 4;
  const int h = col >> 5;
  float4 s = make_float4(0.f, 0.f, 0.f, 0.f);
  float d = 0.f;
  for (int ch = 0; ch < CH; ++ch) {
    const size_t rb = ((size_t)b * CH + ch) * 2048 + n;
    float4 v = *(const float4*)(nump + rb * 128 + col);
    s.x += v.x; s.y += v.y; s.z += v.z; s.w += v.w;
    d += denp[rb * 4 + h];
  }
  float4 o;
  o.x = s.x / d; o.y = s.y / d; o.z = s.z / d; o.w = s.w / d;
  *(float4*)(out + (size_t)t * 4) = o;
}

// ---------------------------------------------------------------------------
extern "C" void kernel_launch(void* const* d_in, const int* in_sizes, int n_in,
                              void* d_out, int out_size, void* d_ws, size_t ws_size,
                              hipStream_t stream) {
  const float* nf   = (const float*)d_in[0];
  const float* Wm   = (const float*)d_in[1];
  const float* bias = (const float*)d_in[2];
  const float* aw   = (const float*)d_in[3];
  float* out = (float*)d_out;
  char* ws = (char*)d_ws;

  // layout (bytes)
  unsigned short* nfh  = (unsigned short*)(ws);            // 2,097,152 (tiled)
  unsigned short* nfm  = (unsigned short*)(ws + 2097152);  // 2,097,152 (tiled)
  unsigned short* vt   = (unsigned short*)(ws + 4194304);  // 2,097,152 (B-frag)
  float*    EFl  = (float*)(ws + 6291456);                 //   262,144
  float*    EFrp = (float*)(ws + 6553600);                 //   262,144
  unsigned* mask = (unsigned*)(ws + 6815744);              // 2,097,152
  const size_t o_den = 8912896;

  // need(CH) = o_den + CH*(4194304 + 131072); CH=8 preferred
  int CH = 8;
  if (ws_size < o_den + 8ull * 4325376ull) CH = 4;

  float* denp = (float*)(ws + o_den);
  float* nump = (float*)(ws + o_den + (size_t)CH * 131072);

  gat_prep<<<256, 256, 0, stream>>>(nf, Wm, bias, aw, nfh, nfm, vt, EFl, EFrp);
  gat_mask<<<2048, 256, 0, stream>>>(nfh, nfm, nf, mask);
  if (CH == 8)
    gat_attn<8><<<1024, 256, 0, stream>>>(vt, EFl, EFrp, mask, nump, denp);
  else
    gat_attn<4><<<512, 256, 0, stream>>>(vt, EFl, EFrp, mask, nump, denp);
  gat_reduce<<<1024, 256, 0, stream>>>(nump, denp, out, CH);
}

// Round 16
// 70.447 us; speedup vs baseline: 1.1084x; 1.1084x over previous
//
#include <hip/hip_runtime.h>
#include <cstdint>
#include <cstddef>

typedef float v16f __attribute__((ext_vector_type(16)));
typedef short v8s  __attribute__((ext_vector_type(8)));

#define MFMA32(A,B,C) __builtin_amdgcn_mfma_f32_32x32x16_bf16((A),(B),(C),0,0,0)
#define THRU 1e-3f

__device__ __forceinline__ unsigned f2bf(float f) {
  unsigned u = __builtin_bit_cast(unsigned, f);
  u += 0x7FFFu + ((u >> 16) & 1u);
  return u >> 16;
}
__device__ __forceinline__ float bf2f(unsigned us) {
  return __builtin_bit_cast(float, us << 16);
}
__device__ __forceinline__ void gload16(const void* g, void* l) {
  __builtin_amdgcn_global_load_lds(
      (const __attribute__((address_space(1))) void*)g,
      (__attribute__((address_space(3))) void*)l, 16, 0, 0);
}

// 32x32 bit-matrix transpose across lanes (ascending-bit convention).
// Input: lane r (both halves identical) holds word M[r] (bit c = entry (r,c)).
// Output: lane c holds word T[c] (bit r = entry (r,c)).
// HD butterfly gives R[r][c]=M[31-c][31-r]; fix with lane-reverse + bit-reverse.
__device__ __forceinline__ unsigned btr32(unsigned x, int lane) {
  const unsigned mj[5] = {0x0000FFFFu, 0x00FF00FFu, 0x0F0F0F0Fu,
                          0x33333333u, 0x55555555u};
  const int js[5] = {16, 8, 4, 2, 1};
#pragma unroll
  for (int s = 0; s < 5; ++s) {
    const int j = js[s];
    const unsigned m = mj[s];
    unsigned xp = (unsigned)__shfl_xor((int)x, j, 64);
    if ((lane & j) == 0) x ^= ((x ^ (xp >> j)) & m);
    else                 x ^= (((xp ^ (x >> j)) & m) << j);
  }
  x = (unsigned)__shfl_xor((int)x, 31, 64);   // lane reverse within half
  return __brev(x);                            // bit reverse
}

// ---------------------------------------------------------------------------
// prep: h = x @ W^T + b; bf16 h/m splits of x in MFMA-tiled layout
// frag[b][t=node/32][kc][lane]{16B}; EFl per-i {El,Fl}; EFrp head-pair
// {Er,Fr,Er',Fr'}; h stored as PV-B-FRAGMENT tiles vt[b][h][jt][f][lane]{8bf16}
// (r11-verified layout: lane&31 = c-col, k = f*16 + (lane>>5)*8 + e).
// ---------------------------------------------------------------------------
__global__ __launch_bounds__(256) void gat_prep(
    const float* __restrict__ nf, const float* __restrict__ Wm,
    const float* __restrict__ bias, const float* __restrict__ aw,
    unsigned short* __restrict__ nfh, unsigned short* __restrict__ nfm,
    unsigned short* __restrict__ vt,
    float* __restrict__ EFl, float* __restrict__ EFrp)
{
  __shared__ float xl[32][132];
  const int tid = threadIdx.x;
  const int row = tid & 31, g = tid >> 5;
  const int r0 = blockIdx.x * 32;          // global node row base (0..8191)
  const int b = r0 >> 11, n0 = r0 & 2047;
  const int d0 = g * 16;

  float x[16];
  {
    const float* xp = nf + (size_t)(r0 + row) * 128 + d0;
#pragma unroll
    for (int q = 0; q < 4; ++q) {
      float4 v = *(const float4*)(xp + 4 * q);
      x[4*q+0] = v.x; x[4*q+1] = v.y; x[4*q+2] = v.z; x[4*q+3] = v.w;
    }
  }
  {
    unsigned hu[16], mu[16];
#pragma unroll
    for (int q = 0; q < 16; ++q) {
      xl[row][d0 + q] = x[q];
      unsigned hb = f2bf(x[q]); float hf = bf2f(hb);
      unsigned mb = f2bf(x[q] - hf);
      hu[q] = hb; mu[q] = mb;
    }
    // tiled fragment store: (b, t=n0>>5, kc=g, lane=row)
    const size_t to = ((size_t)(b * 64 + (n0 >> 5)) * 8 + g) * 512 + row * 8;
    uint4 p0, p1;
    p0.x = hu[0] | (hu[1] << 16);  p0.y = hu[2] | (hu[3] << 16);
    p0.z = hu[4] | (hu[5] << 16);  p0.w = hu[6] | (hu[7] << 16);
    p1.x = hu[8] | (hu[9] << 16);  p1.y = hu[10] | (hu[11] << 16);
    p1.z = hu[12] | (hu[13] << 16); p1.w = hu[14] | (hu[15] << 16);
    *(uint4*)(nfh + to) = p0; *(uint4*)(nfh + to + 256) = p1;
    p0.x = mu[0] | (mu[1] << 16);  p0.y = mu[2] | (mu[3] << 16);
    p0.z = mu[4] | (mu[5] << 16);  p0.w = mu[6] | (mu[7] << 16);
    p1.x = mu[8] | (mu[9] << 16);  p1.y = mu[10] | (mu[11] << 16);
    p1.z = mu[12] | (mu[13] << 16); p1.w = mu[14] | (mu[15] << 16);
    *(uint4*)(nfm + to) = p0; *(uint4*)(nfm + to + 256) = p1;
  }
  __syncthreads();

  float acc[16];
  const int ob = g * 16;
#pragma unroll
  for (int o = 0; o < 16; ++o) acc[o] = bias[ob + o];
  for (int dd = 0; dd < 128; dd += 4) {
    float4 xq = *(const float4*)&xl[row][dd];
#pragma unroll
    for (int o = 0; o < 16; ++o) {
      float4 wq = *(const float4*)(Wm + (size_t)(ob + o) * 128 + dd);
      acc[o] = fmaf(xq.x, wq.x, acc[o]);
      acc[o] = fmaf(xq.y, wq.y, acc[o]);
      acc[o] = fmaf(xq.z, wq.z, acc[o]);
      acc[o] = fmaf(xq.w, wq.w, acc[o]);
    }
  }
  // PV-B-fragment store (r11-verified): j=n0+row; f=(row>>4)&1, kh=(row>>3)&1
  {
    const int f = (row >> 4) & 1, kh = (row >> 3) & 1, e = row & 7;
#pragma unroll
    for (int o = 0; o < 16; ++o) {
      const int c = ob + o, hh2 = c >> 5, cc = c & 31;
      const size_t va = (((size_t)(b * 4 + hh2) * 64 + (n0 >> 5)) * 2 + f) * 512
                        + (kh * 32 + cc) * 8 + e;
      vt[va] = (unsigned short)f2bf(acc[o]);
    }
  }

  const int hh = g >> 1, cb = (g & 1) * 16;
  float sl = 0.f, sr = 0.f;
#pragma unroll
  for (int o = 0; o < 16; ++o) {
    sl = fmaf(acc[o], aw[hh * 64 + cb + o], sl);
    sr = fmaf(acc[o], aw[hh * 64 + 32 + cb + o], sr);
  }
  sl += __shfl_xor(sl, 32, 64);
  sr += __shfl_xor(sr, 32, 64);
  if (!(g & 1)) {
    const float L2E = 1.4426950408889634f;
    float El = exp2f(sl * L2E), Fl = exp2f(sl * (0.3f * L2E));
    float Er = exp2f(sr * L2E), Fr = exp2f(sr * (0.3f * L2E));
    size_t nn = (size_t)(r0 + row);
    EFl[nn * 8 + hh]     = El;
    EFl[nn * 8 + 4 + hh] = Fl;
    // head-pair layout: {Er(2p), Fr(2p), Er(2p+1), Fr(2p+1)} per 16B
    EFrp[nn * 8 + (hh >> 1) * 4 + (hh & 1) * 2]     = Er;
    EFrp[nn * 8 + (hh >> 1) * 4 + (hh & 1) * 2 + 1] = Fr;
  }
}

// ---------------------------------------------------------------------------
// mask (SYMMETRIC): sim is symmetric, so only word-tiles with jw >= iw are
// computed (grid 2048 -> 1088 blocks). Words with jw > iw are additionally
// written transposed (in-wave 32x32 bit transpose) to cover the jw < iw half.
// Ownership: direct = {jw>=iw}, transposed = {jw<iw} — disjoint, complete,
// race-free. f64 inline fix runs before OR/transpose so it propagates.
// mask layout: u32 mask[b][j>>5][i], bit = j&31.
// ---------------------------------------------------------------------------
__global__ __launch_bounds__(256) void gat_mask(
    const unsigned short* __restrict__ nfh, const unsigned short* __restrict__ nfm,
    const float* __restrict__ nf, unsigned* __restrict__ mask)
{
  const int tid = threadIdx.x, lane = tid & 63, wv = tid >> 6;
  const int li = lane & 31, hi = lane >> 5;
  const int blk = blockIdx.x;            // 4 * 272 blocks
  const int b = blk / 272;
  const int p = blk % 272;
  // decode (ib, jb) with jb >= 2*ib; C(ib) = ib*(33-ib) cumulative start
  int ib = 0;
  while (ib < 15 && (ib + 1) * (32 - ib) <= p) ++ib;
  const int jb = 2 * ib + (p - ib * (33 - ib));
  const int i0 = ib * 128 + wv * 32;
  const int j0 = jb * 64;
  const int iw = i0 >> 5;                // 4*ib + wv
  const int jw0 = 2 * jb, jw1 = 2 * jb + 1;
  if (jw1 < iw) return;                  // wave fully below diagonal (owned elsewhere)

  const size_t lbyte = (size_t)lane * 8;
  const size_t tiB  = ((size_t)(b * 64 + (i0 >> 5)) * 8) * 512 + lbyte;
  const size_t tjA0 = ((size_t)(b * 64 + (j0 >> 5)) * 8) * 512 + lbyte;
  const size_t tjA1 = tjA0 + 4096;

  v8s BH[8], BM[8];
#pragma unroll
  for (int kc = 0; kc < 8; ++kc) {
    BH[kc] = *(const v8s*)(nfh + tiB + kc * 512);
    BM[kc] = *(const v8s*)(nfm + tiB + kc * 512);
  }

  v16f S0, S1;
#pragma unroll
  for (int r = 0; r < 16; ++r) { S0[r] = 0.f; S1[r] = 0.f; }
#pragma unroll
  for (int kc = 0; kc < 8; ++kc) {
    v8s A0h = *(const v8s*)(nfh + tjA0 + kc * 512);
    v8s A1h = *(const v8s*)(nfh + tjA1 + kc * 512);
    v8s A0m = *(const v8s*)(nfm + tjA0 + kc * 512);
    v8s A1m = *(const v8s*)(nfm + tjA1 + kc * 512);
    S0 = MFMA32(A0h, BH[kc], S0);
    S1 = MFMA32(A1h, BH[kc], S1);
    S0 = MFMA32(A0h, BM[kc], S0);
    S1 = MFMA32(A1h, BM[kc], S1);
    S0 = MFMA32(A0m, BH[kc], S0);
    S1 = MFMA32(A1m, BH[kc], S1);
  }

  unsigned u0 = 0, u1 = 0;
  float mn = 1e30f;
  const int sh = hi * 4;
#pragma unroll
  for (int r = 0; r < 16; ++r) {
    const int jlc = (r & 3) + 8 * (r >> 2);
    const unsigned bit = (1u << jlc) << sh;
    if (S0[r] > 0.f) u0 |= bit;
    if (S1[r] > 0.f) u1 |= bit;
    mn = fminf(mn, fabsf(S0[r]));
    mn = fminf(mn, fabsf(S1[r]));
  }

  if (mn < THRU) {
    const float* xi = nf + ((size_t)b * 2048 + i0 + li) * 128;
#pragma unroll
    for (int sub = 0; sub < 2; ++sub) {
#pragma unroll
      for (int r = 0; r < 16; ++r) {
        const float s = sub ? S1[r] : S0[r];
        if (fabsf(s) < THRU) {
          const int jlc = (r & 3) + 8 * (r >> 2);
          const int j = j0 + sub * 32 + jlc + 4 * hi;
          const float* xj = nf + ((size_t)b * 2048 + j) * 128;
          double a = 0.0;
          for (int k = 0; k < 128; k += 2) {
            a = fma((double)xi[k],     (double)xj[k],     a);
            a = fma((double)xi[k + 1], (double)xj[k + 1], a);
          }
          const unsigned bit = (1u << jlc) << sh;
          if (sub == 0) u0 = (a > 0.0) ? (u0 | bit) : (u0 & ~bit);
          else          u1 = (a > 0.0) ? (u1 | bit) : (u1 & ~bit);
        }
      }
    }
  }

  unsigned f0 = u0 | (unsigned)__shfl_xor((int)u0, 32, 64);
  unsigned f1 = u1 | (unsigned)__shfl_xor((int)u1, 32, 64);

  // direct writes (jw >= iw)
  if (hi == 0) {
    if (jw0 >= iw) mask[(size_t)(b * 64 + jw0) * 2048 + i0 + li] = f0;
    mask[(size_t)(b * 64 + jw1) * 2048 + i0 + li] = f1;   // jw1 >= iw guaranteed
  }
  // transposed writes (strictly above diagonal -> cover jw < iw half)
  if (jw0 > iw) {
    unsigned T0 = btr32(f0, lane);
    if (hi == 0) mask[(size_t)(b * 64 + iw) * 2048 + jw0 * 32 + li] = T0;
  }
  if (jw1 > iw) {
    unsigned T1 = btr32(f1, lane);
    if (hi == 0) mask[(size_t)(b * 64 + iw) * 2048 + jw1 * 32 + li] = T1;
  }
}

// ---------------------------------------------------------------------------
// attn (r13 hybrid — kept): head-pair split, CH chunks; V = direct-global
// B-fragment loads from vt (L2-resident chunk shared by XCD-grouped blocks);
// EF staged to LDS ONCE (4KB, one barrier total); mask words in registers.
// Main loop: zero barriers, zero LDS-V reads.
// ---------------------------------------------------------------------------
#define PVREG(pw, h, Va, Vb)                                                   \
  {                                                                            \
    auto q0 = __builtin_amdgcn_permlane32_swap((int)pw[0], (int)pw[2], false, false); \
    auto q1 = __builtin_amdgcn_permlane32_swap((int)pw[1], (int)pw[3], false, false); \
    auto q2 = __builtin_amdgcn_permlane32_swap((int)pw[4], (int)pw[6], false, false); \
    auto q3 = __builtin_amdgcn_permlane32_swap((int)pw[5], (int)pw[7], false, false); \
    uint4 c0, c1;                                                              \
    c0.x = (unsigned)q0[0]; c0.y = (unsigned)q1[0];                            \
    c0.z = (unsigned)q0[1]; c0.w = (unsigned)q1[1];                            \
    c1.x = (unsigned)q2[0]; c1.y = (unsigned)q3[0];                            \
    c1.z = (unsigned)q2[1]; c1.w = (unsigned)q3[1];                            \
    v8s P0 = __builtin_bit_cast(v8s, c0);                                      \
    v8s P1 = __builtin_bit_cast(v8s, c1);                                      \
    acc[h] = MFMA32(P0, (Va), acc[h]);                                         \
    acc[h] = MFMA32(P1, (Vb), acc[h]);                                         \
  }

template<int CH>
__global__ __launch_bounds__(256, 2) void gat_attn(
    const unsigned short* __restrict__ vt, const float* __restrict__ EFl,
    const float* __restrict__ EFrp, const unsigned* __restrict__ mask,
    float* __restrict__ nump, float* __restrict__ denp)
{
  constexpr int JPC = 2048 / CH;       // j per chunk
  constexpr int NT = JPC >> 5;         // 32-j tiles per chunk
  __shared__ __align__(16) char sm[JPC * 16];   // EF: 16B per j-node

  const int tid = threadIdx.x, lane = tid & 63, wv = tid >> 6;
  const int li = lane & 31, hi = lane >> 5;

  // XCD swizzle: blocks sharing (b,ch,hp2) — same V/EF chunk — on one XCD.
  const int blk = blockIdx.x;
  const int x = blk & 7, y = blk >> 3;
  const int ig = y & 15;
  const int combo = x * CH + (y >> 4);       // 0..8*CH-1
  const int hp2 = combo & 1;                 // head pair (heads 2hp2, 2hp2+1)
  const int r2 = combo >> 1;
  const int ch = r2 % CH, b = r2 / CH;

  const size_t nb = (size_t)b * 2048;
  const int i0 = ig * 128 + wv * 32;
  const int j0 = ch * JPC;

  float EL[2], FL[2];
  {
    const float* p = EFl + (nb + i0 + li) * 8 + 2 * hp2;
    float2 e = *(const float2*)p;
    float2 f = *(const float2*)(p + 4);
    EL[0] = e.x; EL[1] = e.y; FL[0] = f.x; FL[1] = f.y;
  }

  // prefetch ALL mask words for this wave's i-rows x full j-range
  unsigned mw[NT];
#pragma unroll
  for (int q = 0; q < NT; ++q)
    mw[q] = mask[(size_t)(b * 64 + (j0 >> 5) + q) * 2048 + i0 + li] >> (hi * 4);

  // EF: whole chunk staged once (JPC nodes x 16B)
  for (int q = tid; q < JPC; q += 256)
    gload16((const char*)EFrp + (size_t)(nb + j0 + q) * 32 + (hp2 << 4),
            sm + q * 16);

  v16f acc[2];
#pragma unroll
  for (int h = 0; h < 2; ++h)
#pragma unroll
    for (int r = 0; r < 16; ++r) acc[h][r] = 0.f;
  float den[2] = {0.f, 0.f};

  // V fragment bases (head 2*hp2 and 2*hp2+1); 1KB per (tile,f-half)
  const unsigned short* vb0 =
      vt + ((size_t)(b * 4 + 2 * hp2) * 64 + (j0 >> 5)) * 1024 + (size_t)lane * 8;
  const unsigned short* vb1 = vb0 + 65536;

  __syncthreads();   // EF staged (drains gload_lds)

#pragma unroll 2
  for (int it2 = 0; it2 < NT; ++it2) {
    const unsigned mh = mw[it2];
    v8s V00 = *(const v8s*)(vb0 + it2 * 1024);
    v8s V01 = *(const v8s*)(vb0 + it2 * 1024 + 512);
    v8s V10 = *(const v8s*)(vb1 + it2 * 1024);
    v8s V11 = *(const v8s*)(vb1 + it2 * 1024 + 512);
    const char* Eb = sm + (it2 << 9);
    unsigned pA[8], pB[8];
#pragma unroll
    for (int rp = 0; rp < 8; ++rp) {
      const int r0 = 2 * rp;
      const int jl0c = (r0 & 3) + 8 * (r0 >> 2);
      const int nA = (jl0c + 4 * hi) * 16;
      float4 e0 = *(const float4*)(Eb + nA);        // {Er0,Fr0,Er1,Fr1}
      float4 e1 = *(const float4*)(Eb + nA + 16);   // node jl0c+1
      const bool m0 = (mh >> jl0c) & 1;
      const bool m1 = (mh >> (jl0c + 1)) & 1;
      float wA0 = fmaxf(e0.x * EL[0], e0.y * FL[0]); wA0 = m0 ? wA0 : 0.f;
      float wB0 = fmaxf(e0.z * EL[1], e0.w * FL[1]); wB0 = m0 ? wB0 : 0.f;
      float wA1 = fmaxf(e1.x * EL[0], e1.y * FL[0]); wA1 = m1 ? wA1 : 0.f;
      float wB1 = fmaxf(e1.z * EL[1], e1.w * FL[1]); wB1 = m1 ? wB1 : 0.f;
      den[0] += wA0 + wA1;
      den[1] += wB0 + wB1;
      asm("v_cvt_pk_bf16_f32 %0, %1, %2" : "=v"(pA[rp]) : "v"(wA0), "v"(wA1));
      asm("v_cvt_pk_bf16_f32 %0, %1, %2" : "=v"(pB[rp]) : "v"(wB0), "v"(wB1));
    }
    PVREG(pA, 0, V00, V01)
    PVREG(pB, 1, V10, V11)
  }

#pragma unroll
  for (int h = 0; h < 2; ++h) den[h] += __shfl_xor(den[h], 32, 64);

  const size_t obase = ((size_t)b * CH + ch) * 2048 + i0;
#pragma unroll
  for (int h = 0; h < 2; ++h) {
#pragma unroll
    for (int r = 0; r < 16; ++r) {
      const int il = (r & 3) + 8 * (r >> 2) + 4 * hi;
      nump[(obase + il) * 128 + (hp2 * 2 + h) * 32 + li] = acc[h][r];
    }
  }
  if (lane < 32) {
    float2 dv; dv.x = den[0]; dv.y = den[1];
    *(float2*)(denp + (obase + li) * 4 + 2 * hp2) = dv;
  }
}

// ---------------------------------------------------------------------------
// reduce: out = (sum_ch num) / (sum_ch den), float4-vectorized.
// ---------------------------------------------------------------------------
__global__ __launch_bounds__(256) void gat_reduce(
    const float* __restrict__ nump, const float* __restrict__ denp,
    float* __restrict__ out, const int CH)
{
  const int t = blockIdx.x * 256 + threadIdx.x;   // < 262144
  const int b = t >> 16;
  const int rem = t & 65535;
  const int n = rem >> 5;
  const int col = (rem & 31) * 4;
  const int h = col >> 5;
  float4 s = make_float4(0.f, 0.f, 0.f, 0.f);
  float d = 0.f;
  for (int ch = 0; ch < CH; ++ch) {
    const size_t rb = ((size_t)b * CH + ch) * 2048 + n;
    float4 v = *(const float4*)(nump + rb * 128 + col);
    s.x += v.x; s.y += v.y; s.z += v.z; s.w += v.w;
    d += denp[rb * 4 + h];
  }
  float4 o;
  o.x = s.x / d; o.y = s.y / d; o.z = s.z / d; o.w = s.w / d;
  *(float4*)(out + (size_t)t * 4) = o;
}

// ---------------------------------------------------------------------------
extern "C" void kernel_launch(void* const* d_in, const int* in_sizes, int n_in,
                              void* d_out, int out_size, void* d_ws, size_t ws_size,
                              hipStream_t stream) {
  const float* nf   = (const float*)d_in[0];
  const float* Wm   = (const float*)d_in[1];
  const float* bias = (const float*)d_in[2];
  const float* aw   = (const float*)d_in[3];
  float* out = (float*)d_out;
  char* ws = (char*)d_ws;

  // layout (bytes)
  unsigned short* nfh  = (unsigned short*)(ws);            // 2,097,152 (tiled)
  unsigned short* nfm  = (unsigned short*)(ws + 2097152);  // 2,097,152 (tiled)
  unsigned short* vt   = (unsigned short*)(ws + 4194304);  // 2,097,152 (B-frag)
  float*    EFl  = (float*)(ws + 6291456);                 //   262,144
  float*    EFrp = (float*)(ws + 6553600);                 //   262,144
  unsigned* mask = (unsigned*)(ws + 6815744);              // 2,097,152
  const size_t o_den = 8912896;

  // need(CH) = o_den + CH*(4194304 + 131072); CH=8 preferred
  int CH = 8;
  if (ws_size < o_den + 8ull * 4325376ull) CH = 4;

  float* denp = (float*)(ws + o_den);
  float* nump = (float*)(ws + o_den + (size_t)CH * 131072);

  gat_prep<<<256, 256, 0, stream>>>(nf, Wm, bias, aw, nfh, nfm, vt, EFl, EFrp);
  gat_mask<<<1088, 256, 0, stream>>>(nfh, nfm, nf, mask);
  if (CH == 8)
    gat_attn<8><<<1024, 256, 0, stream>>>(vt, EFl, EFrp, mask, nump, denp);
  else
    gat_attn<4><<<512, 256, 0, stream>>>(vt, EFl, EFrp, mask, nump, denp);
  gat_reduce<<<1024, 256, 0, stream>>>(nump, denp, out, CH);
}